// Round 1
// baseline (111.675 us; speedup 1.0000x reference)
//
#include <hip/hip_runtime.h>

// B=128, K=256, M=8, D=128 ; rows = B*K = 32768 flattened (b,k)
#define LT     20.0f
#define C2EXP  28.853900817779268f   // LT/ln2 : e^(LT*x) = 2^(C2EXP*x)
#define CHUNKS 16                    // 16 chunks x 128 prototype-cols = 2048
#define NBLK   512                   // main grid: 512 blocks x 512 threads

typedef _Float16 half8 __attribute__((ext_vector_type(8)));
typedef float    f32x4 __attribute__((ext_vector_type(4)));

#if __has_builtin(__builtin_amdgcn_exp2f)
#define EXP2F(x) __builtin_amdgcn_exp2f(x)
#else
#define EXP2F(x) __expf(0.69314718055994531f * (x))
#endif

__device__ __forceinline__ float swz16(float x) {
    // xor lane^16 within 32-lane halves (BitMode: xor=16, and=0x1F)
    return __int_as_float(__builtin_amdgcn_ds_swizzle(__float_as_int(x), 0x401F));
}

// ---- prep: f32 P -> f16, packed in exact fragment-consumption lane order.
// half8 slot id = ch*2048 + colq*512 + cfrag*64 + lane
//   c = cfrag&3 (K-slice), h = cfrag>>2 (proto half), n = lane&15, q = lane>>4
//   col  = colq*32 + (n>>2)*8 + (n&3) + 4*h   (prototype col within chunk)
//   gcol = ch*128 + col ; d-range = [c*32 + q*8, +8)
// Main kernel then loads each fragment as ONE fully-coalesced 1KB wave-load.
__global__ __launch_bounds__(256)
void mpcl_prep(const float* __restrict__ P, _Float16* __restrict__ Pw,
               int* __restrict__ ws)
{
    int id = blockIdx.x * 256 + threadIdx.x;     // 0..32767
    if (id == 0) ws[0] = 0;                      // zero gcnt (replaces memset node)
    int ch    = id >> 11;
    int colq  = (id >> 9) & 3;
    int cfrag = (id >> 6) & 7;
    int lane  = id & 63;
    int n = lane & 15, q = lane >> 4;
    int c = cfrag & 3, h = cfrag >> 2;
    int col  = colq * 32 + ((n >> 2) << 3) + (n & 3) + (h << 2);
    int gcol = (ch << 7) + col;
    const float* src = P + ((size_t)gcol << 7) + c * 32 + q * 8;
    float4 a = *(const float4*)src;
    float4 b = *(const float4*)(src + 4);
    half8 hv;
    hv[0] = (_Float16)a.x; hv[1] = (_Float16)a.y;
    hv[2] = (_Float16)a.z; hv[3] = (_Float16)a.w;
    hv[4] = (_Float16)b.x; hv[5] = (_Float16)b.y;
    hv[6] = (_Float16)b.z; hv[7] = (_Float16)b.w;
    *(half8*)(Pw + (size_t)id * 8) = hv;
}

// Grid: 512 blocks x 512 thr (8 waves). Block owns 64 rows x all 2048 cols.
// wave w: rg=w>>2 (32-row group), colq=w&3 (4 concepts per 128-col chunk).
// A-fragments read straight from L2-resident packed Pw into registers,
// double-buffered; NO LDS staging, NO barriers in the K-loop.
// C-layout lane(q,n) reg j: concept colq*4+q, proto j (acc1) / 4+j (acc2),
// col n = V row  -> full softmax-over-8 stays in-lane.
__global__ __launch_bounds__(512, 4)
void mpcl_main(const float* __restrict__ V,        // (32768, 128) f32
               const int*   __restrict__ labels,   // (32768)
               const _Float16* __restrict__ Pw,    // packed P (prep)
               int* __restrict__ ws,               // [0]=gcnt ; +256B: partials
               float* __restrict__ out)
{
    __shared__ float sh_denom[64];
    __shared__ float sh_simpos[64];
    __shared__ float sh_fin[16];
    __shared__ int   sh_last;

    int*   gcnt = ws;
    float* part = (float*)((char*)ws + 256);

    const int tid  = threadIdx.x;
    const int lane = tid & 63;
    const int w    = tid >> 6;        // 0..7
    const int colq = w & 3;
    const int rg   = w >> 2;          // 0..1
    const int n    = lane & 15;
    const int q    = lane >> 4;
    const int rowbase = blockIdx.x * 64;

    if (tid < 64) { sh_denom[tid] = 0.0f; sh_simpos[tid] = 0.0f; }

    int lab = 0;
    if (tid < 64) lab = labels[rowbase + tid];    // prefetch early

    // ---- V fragments (B operand), f16, register-resident ----
    half8 vh[2][4];
#pragma unroll
    for (int rf = 0; rf < 2; ++rf) {
        const float* vr = V + ((size_t)(rowbase + rg * 32 + rf * 16 + n) << 7) + q * 8;
#pragma unroll
        for (int c = 0; c < 4; ++c) {
            float4 x0 = *(const float4*)(vr + c * 32);
            float4 x1 = *(const float4*)(vr + c * 32 + 4);
            vh[rf][c][0] = (_Float16)x0.x; vh[rf][c][1] = (_Float16)x0.y;
            vh[rf][c][2] = (_Float16)x0.z; vh[rf][c][3] = (_Float16)x0.w;
            vh[rf][c][4] = (_Float16)x1.x; vh[rf][c][5] = (_Float16)x1.y;
            vh[rf][c][6] = (_Float16)x1.z; vh[rf][c][7] = (_Float16)x1.w;
        }
    }
    __syncthreads();   // sh_* initialized before any epilogue writes (only pre-loop barrier)

    // lane's half8 slot: id = ch*2048 + colq*512 + f*64 + lane
    const half8* pw = (const half8*)Pw + (size_t)colq * 512 + lane;

    const int rowk0 = (rowbase + rg * 32 + n) & 255;        // positive concept, rf=0
    const int rowk1 = (rowbase + rg * 32 + 16 + n) & 255;   // rf=1

    float dn0 = 0.f, dn1 = 0.f;

    half8 bufA[8], bufB[8];
#pragma unroll
    for (int f = 0; f < 8; ++f) bufA[f] = pw[f * 64];

#define COMPUTE(BUF, CABASE) do {                                               \
    f32x4 acc1[2] = {{0.f,0.f,0.f,0.f},{0.f,0.f,0.f,0.f}};                      \
    f32x4 acc2[2] = {{0.f,0.f,0.f,0.f},{0.f,0.f,0.f,0.f}};                      \
    _Pragma("unroll")                                                           \
    for (int c = 0; c < 4; ++c) {                                               \
        acc1[0] = __builtin_amdgcn_mfma_f32_16x16x32_f16(BUF[c],   vh[0][c], acc1[0], 0, 0, 0); \
        acc1[1] = __builtin_amdgcn_mfma_f32_16x16x32_f16(BUF[c],   vh[1][c], acc1[1], 0, 0, 0); \
        acc2[0] = __builtin_amdgcn_mfma_f32_16x16x32_f16(BUF[4+c], vh[0][c], acc2[0], 0, 0, 0); \
        acc2[1] = __builtin_amdgcn_mfma_f32_16x16x32_f16(BUF[4+c], vh[1][c], acc2[1], 0, 0, 0); \
    }                                                                           \
    _Pragma("unroll")                                                           \
    for (int rf = 0; rf < 2; ++rf) {                                            \
        float x0 = acc1[rf][0], x1 = acc1[rf][1], x2 = acc1[rf][2], x3 = acc1[rf][3]; \
        float x4 = acc2[rf][0], x5 = acc2[rf][1], x6 = acc2[rf][2], x7 = acc2[rf][3]; \
        float e0 = EXP2F(C2EXP * x0), e1 = EXP2F(C2EXP * x1);                   \
        float e2 = EXP2F(C2EXP * x2), e3 = EXP2F(C2EXP * x3);                   \
        float e4 = EXP2F(C2EXP * x4), e5 = EXP2F(C2EXP * x5);                   \
        float e6 = EXP2F(C2EXP * x6), e7 = EXP2F(C2EXP * x7);                   \
        float es = ((e0 + e1) + (e2 + e3)) + ((e4 + e5) + (e6 + e7));           \
        float ss = fmaf(e0, x0, fmaf(e1, x1, fmaf(e2, x2, e3 * x3)))            \
                 + fmaf(e4, x4, fmaf(e5, x5, fmaf(e6, x6, e7 * x7)));           \
        float simc = __fdividef(ss, es);                                        \
        if (rf) dn1 += EXP2F(C2EXP * simc); else dn0 += EXP2F(C2EXP * simc);    \
        if ((CABASE) == (rf ? rowk1 : rowk0))                                   \
            sh_simpos[rg * 32 + rf * 16 + n] = simc;   /* unique writer */      \
    }                                                                           \
} while (0)

    int cA = colq * 4 + q;
#pragma unroll 1
    for (int ch = 0; ch < CHUNKS; ch += 2) {
        // prefetch chunk ch+1 into bufB (lands under COMPUTE(bufA))
#pragma unroll
        for (int f = 0; f < 8; ++f) bufB[f] = pw[(ch + 1) * 2048 + f * 64];

        COMPUTE(bufA, cA);

        if (ch + 2 < CHUNKS) {   // prefetch chunk ch+2 into bufA
#pragma unroll
            for (int f = 0; f < 8; ++f) bufA[f] = pw[(ch + 2) * 2048 + f * 64];
        }

        COMPUTE(bufB, cA + 16);
        cA += 32;
    }

    // ---- fold denominators over the 4 q-groups (distinct concepts) ----
#pragma unroll
    for (int rf = 0; rf < 2; ++rf) {
        float t = rf ? dn1 : dn0;
        t += swz16(t);
        t += __shfl_xor(t, 32);
        if (lane < 16)
            atomicAdd(&sh_denom[rg * 32 + rf * 16 + n], t);
    }
    __syncthreads();

    // ---- in-block loss over 64 rows ----
    float s = 0.f, cc = 0.f;
    if (tid < 64) {
        float lp = logf(sh_denom[tid] + 1e-8f) - LT * (sh_simpos[tid] + 0.05f);
        float mk = (lab == 1) ? 1.0f : 0.0f;
        s = lp * mk;
        cc = mk;
    }
#pragma unroll
    for (int off = 32; off >= 1; off >>= 1) {
        s  += __shfl_down(s, off);
        cc += __shfl_down(cc, off);
    }

    // ---- uncontended per-block partials + counter; last block finalizes ----
    if (tid == 0) {
        __hip_atomic_store(&part[2 * blockIdx.x],     s,  __ATOMIC_RELAXED, __HIP_MEMORY_SCOPE_AGENT);
        __hip_atomic_store(&part[2 * blockIdx.x + 1], cc, __ATOMIC_RELAXED, __HIP_MEMORY_SCOPE_AGENT);
        __threadfence();
        int g = __hip_atomic_fetch_add(gcnt, 1, __ATOMIC_ACQ_REL, __HIP_MEMORY_SCOPE_AGENT);
        sh_last = (g == NBLK - 1);
    }
    __syncthreads();
    if (sh_last) {
        float ts = 0.f, tc = 0.f;
        for (int i = tid; i < NBLK; i += 512) {
            ts += __hip_atomic_load(&part[2 * i],     __ATOMIC_RELAXED, __HIP_MEMORY_SCOPE_AGENT);
            tc += __hip_atomic_load(&part[2 * i + 1], __ATOMIC_RELAXED, __HIP_MEMORY_SCOPE_AGENT);
        }
#pragma unroll
        for (int off = 32; off >= 1; off >>= 1) {
            ts += __shfl_down(ts, off);
            tc += __shfl_down(tc, off);
        }
        if (lane == 0) { sh_fin[w] = ts; sh_fin[8 + w] = tc; }
        __syncthreads();
        if (tid == 0) {
            ts = 0.f; tc = 0.f;
#pragma unroll
            for (int i = 0; i < 8; ++i) { ts += sh_fin[i]; tc += sh_fin[8 + i]; }
            out[0] = (tc > 0.0f) ? (ts / tc) : ts;
        }
    }
}

extern "C" void kernel_launch(void* const* d_in, const int* in_sizes, int n_in,
                              void* d_out, int out_size, void* d_ws, size_t ws_size,
                              hipStream_t stream)
{
    const float* V      = (const float*)d_in[0];
    const int*   labels = (const int*)d_in[1];
    const float* P      = (const float*)d_in[2];
    float* out = (float*)d_out;
    int*   ws  = (int*)d_ws;
    _Float16* Pw = (_Float16*)((char*)d_ws + 16384);   // 512 KB packed P

    mpcl_prep<<<128, 256, 0, stream>>>(P, Pw, ws);     // also zeroes gcnt
    mpcl_main<<<NBLK, 512, 0, stream>>>(V, labels, Pw, ws, out);
}

// Round 2
// 108.918 us; speedup vs baseline: 1.0253x; 1.0253x over previous
//
#include <hip/hip_runtime.h>

// B=128, K=256, M=8, D=128 ; rows = B*K = 32768 flattened (b,k)
#define LT     20.0f
#define C2EXP  28.853900817779268f   // LT/ln2 : e^(LT*x) = 2^(C2EXP*x)
#define CHUNKS 16                    // 16 chunks x 128 prototype-cols = 2048
#define NBLK   512                   // main grid: 512 blocks x 512 threads

typedef _Float16 half8 __attribute__((ext_vector_type(8)));
typedef float    f32x4 __attribute__((ext_vector_type(4)));

#if __has_builtin(__builtin_amdgcn_exp2f)
#define EXP2F(x) __builtin_amdgcn_exp2f(x)
#else
#define EXP2F(x) __expf(0.69314718055994531f * (x))
#endif

__device__ __forceinline__ float swz16(float x) {
    // xor lane^16 within 32-lane halves (BitMode: xor=16, and=0x1F)
    return __int_as_float(__builtin_amdgcn_ds_swizzle(__float_as_int(x), 0x401F));
}

// async global->LDS, 16B per lane; lds base must be wave-uniform
#define GLD16(gp, lp) __builtin_amdgcn_global_load_lds( \
    (const __attribute__((address_space(1))) void*)(gp), \
    (__attribute__((address_space(3))) void*)(lp), 16, 0, 0)

// ---- prep: f32 P -> f16, packed in exact fragment-consumption lane order.
// half8 slot id = ch*2048 + colq*512 + cfrag*64 + lane
//   c = cfrag&3 (K-slice), h = cfrag>>2 (proto half), n = lane&15, q = lane>>4
//   col  = colq*32 + (n>>2)*8 + (n&3) + 4*h   (prototype col within chunk)
//   gcol = ch*128 + col ; d-range = [c*32 + q*8, +8)
// -> global_load_lds staging AND ds_read_b128 fragment reads are both
//    perfectly lane-linear: zero bank conflicts, no swizzle math.
__global__ __launch_bounds__(256)
void mpcl_prep(const float* __restrict__ P, _Float16* __restrict__ Pw,
               int* __restrict__ ws)
{
    int id = blockIdx.x * 256 + threadIdx.x;     // 0..32767
    if (id == 0) ws[0] = 0;                      // zero gcnt (replaces memset node)
    int ch    = id >> 11;
    int colq  = (id >> 9) & 3;
    int cfrag = (id >> 6) & 7;
    int lane  = id & 63;
    int n = lane & 15, q = lane >> 4;
    int c = cfrag & 3, h = cfrag >> 2;
    int col  = colq * 32 + ((n >> 2) << 3) + (n & 3) + (h << 2);
    int gcol = (ch << 7) + col;
    const float* src = P + ((size_t)gcol << 7) + c * 32 + q * 8;
    float4 a = *(const float4*)src;
    float4 b = *(const float4*)(src + 4);
    half8 hv;
    hv[0] = (_Float16)a.x; hv[1] = (_Float16)a.y;
    hv[2] = (_Float16)a.z; hv[3] = (_Float16)a.w;
    hv[4] = (_Float16)b.x; hv[5] = (_Float16)b.y;
    hv[6] = (_Float16)b.z; hv[7] = (_Float16)b.w;
    *(half8*)(Pw + (size_t)id * 8) = hv;
}

// Grid: 512 blocks x 512 thr (8 waves). Block owns 64 rows x all 2048 cols.
// wave w: rg=w>>2 (32-row group), colq=w&3 (4 concepts per 128-col chunk).
// Shared LDS staging of each 32KB chunk (all 8 waves cooperate), double
// buffered, 1 barrier per chunk, 2 blocks/CU so barrier bubbles are filled
// by the co-resident block. A-fragments: conflict-free lane-linear
// ds_read_b128. V stays register-resident (reused all 16 chunks).
// amdgpu_waves_per_eu(4,4): pin VGPR budget at 128 so the allocator does
// NOT squeeze to 64 and spill vh/buffers to scratch (rounds 0/1 pathology:
// VGPR 48/64 + 2.1MB scratch write leak).
__global__ __attribute__((amdgpu_flat_work_group_size(512, 512),
                          amdgpu_waves_per_eu(4, 4)))
void mpcl_main(const float* __restrict__ V,        // (32768, 128) f32
               const int*   __restrict__ labels,   // (32768)
               const _Float16* __restrict__ Pw,    // packed P (prep)
               int* __restrict__ ws,               // [0]=gcnt ; +256B: partials
               float* __restrict__ out)
{
    __shared__ __align__(16) _Float16 Pst[2][2048 * 8];   // 2 x 32 KB
    __shared__ float sh_denom[64];
    __shared__ float sh_simpos[64];
    __shared__ float sh_fin[16];
    __shared__ int   sh_last;

    int*   gcnt = ws;
    float* part = (float*)((char*)ws + 256);

    const int tid  = threadIdx.x;
    const int lane = tid & 63;
    const int w    = tid >> 6;        // 0..7
    const int colq = w & 3;
    const int rg   = w >> 2;          // 0..1
    const int n    = lane & 15;
    const int q    = lane >> 4;
    const int rowbase = blockIdx.x * 64;

    if (tid < 64) { sh_denom[tid] = 0.0f; sh_simpos[tid] = 0.0f; }

    int lab = 0;
    if (tid < 64) lab = labels[rowbase + tid];    // prefetch early

    // ---- staging map: wave w stages half8 slots [w*256, w*256+256) of each
    // chunk: 4 x GLD16 per wave per chunk, lane-linear. ----
    const _Float16* gbase = Pw + (size_t)(w * 256 + lane) * 8;

#define STAGE(CH, B) do {                                       \
    const _Float16* g_ = gbase + (size_t)(CH) * 16384;          \
    _Float16* l_ = &Pst[B][(w * 256) * 8];                      \
    GLD16(g_,        l_);                                       \
    GLD16(g_ +  512, l_ +  512);                                \
    GLD16(g_ + 1024, l_ + 1024);                                \
    GLD16(g_ + 1536, l_ + 1536);                                \
} while (0)

    STAGE(0, 0);   // chunk 0 in flight; drained by first barrier

    // ---- V fragments (B operand), f16, register-resident (32 VGPR) ----
    half8 vh[2][4];
#pragma unroll
    for (int rf = 0; rf < 2; ++rf) {
        const float* vr = V + ((size_t)(rowbase + rg * 32 + rf * 16 + n) << 7) + q * 8;
#pragma unroll
        for (int c = 0; c < 4; ++c) {
            float4 x0 = *(const float4*)(vr + c * 32);
            float4 x1 = *(const float4*)(vr + c * 32 + 4);
            vh[rf][c][0] = (_Float16)x0.x; vh[rf][c][1] = (_Float16)x0.y;
            vh[rf][c][2] = (_Float16)x0.z; vh[rf][c][3] = (_Float16)x0.w;
            vh[rf][c][4] = (_Float16)x1.x; vh[rf][c][5] = (_Float16)x1.y;
            vh[rf][c][6] = (_Float16)x1.z; vh[rf][c][7] = (_Float16)x1.w;
        }
    }

    const int rowk0 = (rowbase + rg * 32 + n) & 255;        // positive concept, rf=0
    const int rowk1 = (rowbase + rg * 32 + 16 + n) & 255;   // rf=1
    const int aoff  = (colq * 512 + lane) * 8;              // half index of a1(c=0)

    float dn0 = 0.f, dn1 = 0.f;
    int cA = colq * 4 + q;

#pragma unroll 1
    for (int ch = 0; ch < CHUNKS; ++ch) {
        __syncthreads();   // drains vmcnt: chunk ch staged & visible

        if (ch + 1 < CHUNKS) STAGE(ch + 1, (ch + 1) & 1);   // overlap with compute

        const _Float16* base = &Pst[ch & 1][0];

        f32x4 acc1[2] = {{0.f,0.f,0.f,0.f},{0.f,0.f,0.f,0.f}};
        f32x4 acc2[2] = {{0.f,0.f,0.f,0.f},{0.f,0.f,0.f,0.f}};
#pragma unroll
        for (int c = 0; c < 4; ++c) {
            half8 a1 = *(const half8*)&base[aoff + c * 512];          // frag c
            half8 a2 = *(const half8*)&base[aoff + c * 512 + 2048];   // frag 4+c
            acc1[0] = __builtin_amdgcn_mfma_f32_16x16x32_f16(a1, vh[0][c], acc1[0], 0, 0, 0);
            acc1[1] = __builtin_amdgcn_mfma_f32_16x16x32_f16(a1, vh[1][c], acc1[1], 0, 0, 0);
            acc2[0] = __builtin_amdgcn_mfma_f32_16x16x32_f16(a2, vh[0][c], acc2[0], 0, 0, 0);
            acc2[1] = __builtin_amdgcn_mfma_f32_16x16x32_f16(a2, vh[1][c], acc2[1], 0, 0, 0);
        }

        // ---- epilogue: full softmax-over-8 in-lane, no cross-lane ops ----
#pragma unroll
        for (int rf = 0; rf < 2; ++rf) {
            float x0 = acc1[rf][0], x1 = acc1[rf][1], x2 = acc1[rf][2], x3 = acc1[rf][3];
            float x4 = acc2[rf][0], x5 = acc2[rf][1], x6 = acc2[rf][2], x7 = acc2[rf][3];
            float e0 = EXP2F(C2EXP * x0), e1 = EXP2F(C2EXP * x1);
            float e2 = EXP2F(C2EXP * x2), e3 = EXP2F(C2EXP * x3);
            float e4 = EXP2F(C2EXP * x4), e5 = EXP2F(C2EXP * x5);
            float e6 = EXP2F(C2EXP * x6), e7 = EXP2F(C2EXP * x7);
            float es = ((e0 + e1) + (e2 + e3)) + ((e4 + e5) + (e6 + e7));
            float ss = fmaf(e0, x0, fmaf(e1, x1, fmaf(e2, x2, e3 * x3)))
                     + fmaf(e4, x4, fmaf(e5, x5, fmaf(e6, x6, e7 * x7)));
            float simc = __fdividef(ss, es);
            if (rf) dn1 += EXP2F(C2EXP * simc); else dn0 += EXP2F(C2EXP * simc);
            if (cA == (rf ? rowk1 : rowk0))
                sh_simpos[rg * 32 + rf * 16 + n] = simc;   // unique writer per row
        }
        cA += 16;
    }

    // ---- fold denominators over the 4 q-groups (distinct concepts) ----
#pragma unroll
    for (int rf = 0; rf < 2; ++rf) {
        float t = rf ? dn1 : dn0;
        t += swz16(t);
        t += __shfl_xor(t, 32);
        if (lane < 16)
            atomicAdd(&sh_denom[rg * 32 + rf * 16 + n], t);
    }
    __syncthreads();

    // ---- in-block loss over 64 rows ----
    float s = 0.f, cc = 0.f;
    if (tid < 64) {
        float lp = logf(sh_denom[tid] + 1e-8f) - LT * (sh_simpos[tid] + 0.05f);
        float mk = (lab == 1) ? 1.0f : 0.0f;
        s = lp * mk;
        cc = mk;
    }
#pragma unroll
    for (int off = 32; off >= 1; off >>= 1) {
        s  += __shfl_down(s, off);
        cc += __shfl_down(cc, off);
    }

    // ---- uncontended per-block partials + counter; last block finalizes ----
    if (tid == 0) {
        __hip_atomic_store(&part[2 * blockIdx.x],     s,  __ATOMIC_RELAXED, __HIP_MEMORY_SCOPE_AGENT);
        __hip_atomic_store(&part[2 * blockIdx.x + 1], cc, __ATOMIC_RELAXED, __HIP_MEMORY_SCOPE_AGENT);
        __threadfence();
        int g = __hip_atomic_fetch_add(gcnt, 1, __ATOMIC_ACQ_REL, __HIP_MEMORY_SCOPE_AGENT);
        sh_last = (g == NBLK - 1);
    }
    __syncthreads();
    if (sh_last) {
        float ts = 0.f, tc = 0.f;
        for (int i = tid; i < NBLK; i += 512) {
            ts += __hip_atomic_load(&part[2 * i],     __ATOMIC_RELAXED, __HIP_MEMORY_SCOPE_AGENT);
            tc += __hip_atomic_load(&part[2 * i + 1], __ATOMIC_RELAXED, __HIP_MEMORY_SCOPE_AGENT);
        }
#pragma unroll
        for (int off = 32; off >= 1; off >>= 1) {
            ts += __shfl_down(ts, off);
            tc += __shfl_down(tc, off);
        }
        if (lane == 0) { sh_fin[w] = ts; sh_fin[8 + w] = tc; }
        __syncthreads();
        if (tid == 0) {
            ts = 0.f; tc = 0.f;
#pragma unroll
            for (int i = 0; i < 8; ++i) { ts += sh_fin[i]; tc += sh_fin[8 + i]; }
            out[0] = (tc > 0.0f) ? (ts / tc) : ts;
        }
    }
}

extern "C" void kernel_launch(void* const* d_in, const int* in_sizes, int n_in,
                              void* d_out, int out_size, void* d_ws, size_t ws_size,
                              hipStream_t stream)
{
    const float* V      = (const float*)d_in[0];
    const int*   labels = (const int*)d_in[1];
    const float* P      = (const float*)d_in[2];
    float* out = (float*)d_out;
    int*   ws  = (int*)d_ws;
    _Float16* Pw = (_Float16*)((char*)d_ws + 16384);   // 512 KB packed P

    mpcl_prep<<<128, 256, 0, stream>>>(P, Pw, ws);     // also zeroes gcnt
    mpcl_main<<<NBLK, 512, 0, stream>>>(V, labels, Pw, ws, out);
}